// Round 18
// baseline (241.886 us; speedup 1.0000x reference)
//
#include <hip/hip_runtime.h>
#include <hip/hip_bf16.h>
#include <math.h>

typedef unsigned short u16;
typedef __attribute__((ext_vector_type(8))) short bf16x8;
typedef __attribute__((ext_vector_type(4))) float f32x4;
typedef __attribute__((ext_vector_type(16))) float f32x16;
typedef __attribute__((ext_vector_type(4))) unsigned int u32x4;

#define BATCH 4
#define TSEQ  2048
#define HEADS 16
#define DK    64
#define EMB   1024
#define MROWS 8192            // B*T
#define NQKV  3072
#define PHT   ((size_t)MROWS * EMB)   // 8388608 elems per Q/K/V plane

__device__ __forceinline__ u16 f2bf(float f) {
    union { float f; unsigned int i; } v;
    v.f = f;
    unsigned int x = v.i;
    return (u16)((x + 0x7FFFu + ((x >> 16) & 1u)) >> 16);  // RNE
}

// packed 2xfp32 -> 2xbf16 (RNE) in one u32
__device__ __forceinline__ unsigned int pk2bf(float a, float b) {
    float2 f2; f2.x = a; f2.y = b;
    union { __hip_bfloat162 h; unsigned int u; } cv;
    cv.h = __float22bfloat162_rn(f2);
    return cv.u;
}

// async 16B global->LDS (dest = wave-uniform base + lane*16)
__device__ __forceinline__ void gl2lds16(const u16* g, u16* l) {
    __builtin_amdgcn_global_load_lds(
        (const __attribute__((address_space(1))) unsigned int*)g,
        (__attribute__((address_space(3))) unsigned int*)l, 16, 0, 0);
}

// ---------------------------------------------------------------------------
// prep: fp32 -> bf16 convert (X); both weight transposes in ONE launch
// ---------------------------------------------------------------------------
__global__ __launch_bounds__(256) void convert_x(const float* __restrict__ X,
                                                 u16* __restrict__ Xb) {
    int i = (blockIdx.x * 256 + threadIdx.x) * 4;
    float4 v = *(const float4*)&X[i];
    ushort4 o;
    o.x = f2bf(v.x); o.y = f2bf(v.y); o.z = f2bf(v.z); o.w = f2bf(v.w);
    *(ushort4*)&Xb[i] = o;
}

// bx < 96 -> Wqkv (N=3072); else Wo (N=1024). K=1024 for both.
__global__ __launch_bounds__(256) void transpose_both(const float* __restrict__ Wqkv,
                                                      const float* __restrict__ Wo,
                                                      u16* __restrict__ Wt,
                                                      u16* __restrict__ Wot) {
    __shared__ float tile[32][33];
    const int tx = threadIdx.x & 31, ty = threadIdx.x >> 5;  // 32 x 8
    const int K = 1024;
    const float* W;
    u16* D;
    int N, bx;
    if (blockIdx.x < 96) { W = Wqkv; D = Wt; N = 3072; bx = blockIdx.x; }
    else                 { W = Wo;   D = Wot; N = 1024; bx = blockIdx.x - 96; }
    const int by = blockIdx.y;
#pragma unroll
    for (int s = 0; s < 4; s++)
        tile[ty + 8 * s][tx] = W[(size_t)(by * 32 + ty + 8 * s) * N + bx * 32 + tx];
    __syncthreads();
#pragma unroll
    for (int s = 0; s < 4; s++)
        D[(size_t)(bx * 32 + ty + 8 * s) * K + by * 32 + tx] = f2bf(tile[tx][ty + 8 * s]);
}

// ---------------------------------------------------------------------------
// MFMA GEMM core v3 (verified; used by gemm2): 128x256 tile, BK=64, 8 waves,
// triple-buffered LDS + counted vmcnt + register-fragment double-buffer.
// ---------------------------------------------------------------------------
template <int KDIM>
__device__ __forceinline__ void gemm_core256(const u16* __restrict__ A,
                                             const u16* __restrict__ Bt,
                                             u16* pool,
                                             int m0, int n0, int wm, int wn,
                                             int tid, int lo, int quad,
                                             f32x4 (&acc)[4][4]) {
    constexpr int NT = KDIM / 64;          // 16 K-tiles
    static_assert(NT >= 4 && (NT % 2) == 0, "NT even, >=4");

    const u16* ga[2];
    const u16* gb[4];
#pragma unroll
    for (int c = 0; c < 2; c++) {
        int chunk = c * 512 + tid, row = chunk >> 3, p = chunk & 7;
        ga[c] = A + (size_t)(m0 + row) * KDIM + (p ^ (row & 7)) * 8;
    }
#pragma unroll
    for (int c = 0; c < 4; c++) {
        int chunk = c * 512 + tid, row = chunk >> 3, p = chunk & 7;
        gb[c] = Bt + (size_t)(n0 + row) * KDIM + (p ^ (row & 7)) * 8;
    }

    auto stage = [&](int b) {   // 6 gl2lds per thread -> vmcnt +6
        u16* As = pool + b * 24576;
        u16* Bs = As + 8192;
#pragma unroll
        for (int c = 0; c < 2; c++) {
            gl2lds16(ga[c], As + (size_t)(c * 512 + tid) * 8);
            ga[c] += 64;
        }
#pragma unroll
        for (int c = 0; c < 4; c++) {
            gl2lds16(gb[c], Bs + (size_t)(c * 512 + tid) * 8);
            gb[c] += 64;
        }
    };

    bf16x8 afA[2][4], bwA[2][4], afB[2][4], bwB[2][4];

    auto ldfrag = [&](int b, bf16x8 (&af)[2][4], bf16x8 (&bw)[2][4]) {
        const u16* As = pool + b * 24576;
        const u16* Bs = As + 8192;
#pragma unroll
        for (int ks = 0; ks < 2; ks++) {
#pragma unroll
            for (int i = 0; i < 4; i++) {
                int r = wm + i * 16 + lo;
                af[ks][i] = *(const bf16x8*)&As[r * 64 + ((ks * 4 + quad) ^ (r & 7)) * 8];
            }
#pragma unroll
            for (int j = 0; j < 4; j++) {
                int r = wn + j * 16 + lo;
                bw[ks][j] = *(const bf16x8*)&Bs[r * 64 + ((ks * 4 + quad) ^ (r & 7)) * 8];
            }
        }
    };

    auto domfma = [&](bf16x8 (&af)[2][4], bf16x8 (&bw)[2][4]) {
        __builtin_amdgcn_sched_barrier(0);
        __builtin_amdgcn_s_setprio(1);
#pragma unroll
        for (int ks = 0; ks < 2; ks++)
#pragma unroll
            for (int i = 0; i < 4; i++)
#pragma unroll
                for (int j = 0; j < 4; j++)
                    acc[i][j] = __builtin_amdgcn_mfma_f32_16x16x32_bf16(
                        af[ks][i], bw[ks][j], acc[i][j], 0, 0, 0);
        __builtin_amdgcn_s_setprio(0);
    };

    stage(0); stage(1); stage(2);            // 18 loads in flight
    asm volatile("s_waitcnt vmcnt(12)" ::: "memory");
    __builtin_amdgcn_s_barrier();
    ldfrag(0, afA, bwA);

#pragma unroll
    for (int kt = 0; kt < NT; kt++) {
        if (kt < NT - 1) {
            asm volatile("s_waitcnt lgkmcnt(0)" ::: "memory");
            if (kt < NT - 2)
                asm volatile("s_waitcnt vmcnt(6)" ::: "memory");
            else
                asm volatile("s_waitcnt vmcnt(0)" ::: "memory");
            __builtin_amdgcn_s_barrier();
            if (kt + 3 < NT) stage(kt % 3);
            if (kt & 1) ldfrag((kt + 1) % 3, afA, bwA);
            else        ldfrag((kt + 1) % 3, afB, bwB);
        }
        if (kt & 1) domfma(afB, bwB);
        else        domfma(afA, bwA);
    }
}

// ---------------------------------------------------------------------------
// GEMM1 core v5: 8-PHASE 256x256 schedule (m201 port). BK=64, 8 waves
// (2Mx4N, wave output 128x64), 512 thr, LDS 128KB = 2 dbuf x (A 256x64 +
// B 256x64). Per K-tile: 4 quadrant-phases, each
//   B1-barrier -> ds_read (q0: 8 B-frags + 4 A-frags; else 4 A-frags)
//   -> stage 1 half-tile (2 gl2lds) -> lgkmcnt(0) -> B2-barrier
//   -> setprio(1) 16 MFMA setprio(0)
// Stage schedule: q0: A-half0(kt+1), q1: A-half1(kt+1), q2: B-half0(kt+2),
// q3: B-half1(kt+2).  Region safety: B-halves of tile kt last read at q0
// (overwritten q2/q3: 2 barriers later); A-halves last read at q3
// (overwritten next tile's q0/q1). vmcnt(4) once per tile at q0 (= B halves
// of kt+1 still in flight); vmcnt(0) at the last tile.
// Swizzle: same verified chunk-XOR p^(row&7) as v3 (2-way b128 reads).
// ---------------------------------------------------------------------------
template <int KDIM>
__device__ __forceinline__ void gemm_core_8ph(const u16* __restrict__ A,
                                              const u16* __restrict__ Bt,
                                              u16* pool,
                                              int m0, int n0, int wm, int wn,
                                              int tid, int lo, int quad,
                                              f32x4 (&acc)[8][4]) {
    constexpr int NT = KDIM / 64;          // 16 K-tiles

    // staging base pointers: [half h][load c]; dest chunk = (c*512+tid)
    const u16* gA[2][2];
    const u16* gB[2][2];
    int dstoff[2];
#pragma unroll
    for (int c = 0; c < 2; c++) {
        int chunk = c * 512 + tid;          // 0..1023 within a 128x64 half
        int row = chunk >> 3, p = chunk & 7;
        int pg = p ^ (row & 7);
        dstoff[c] = chunk * 8;
#pragma unroll
        for (int h = 0; h < 2; h++) {
            gA[h][c] = A  + (size_t)(m0 + h * 128 + row) * KDIM + pg * 8;
            gB[h][c] = Bt + (size_t)(n0 + h * 128 + row) * KDIM + pg * 8;
        }
    }

    // stage half: op 0=A,1=B of tile kt, half h -> buf kt&1  (2 loads)
    auto stageHalf = [&](int op, int kt, int h) {
        u16* base = pool + (kt & 1) * 32768 + op * 16384 + h * 8192;
        const u16* g0 = (op ? gB : gA)[h][0] + kt * 64;
        const u16* g1 = (op ? gB : gA)[h][1] + kt * 64;
        gl2lds16(g0, base + dstoff[0]);
        gl2lds16(g1, base + dstoff[1]);
    };

    // prologue: tile0 complete (8 loads) + B-halves of tile1 (4 loads)
    stageHalf(0, 0, 0); stageHalf(0, 0, 1);
    stageHalf(1, 0, 0); stageHalf(1, 0, 1);
    stageHalf(1, 1, 0); stageHalf(1, 1, 1);

    bf16x8 bw[2][4];

    for (int kt = 0; kt < NT; kt++) {
        const u16* At = pool + (kt & 1) * 32768;
        const u16* Bb = At + 16384;
#pragma unroll
        for (int q = 0; q < 4; q++) {
            if (q == 0) {
                if (kt < NT - 1) asm volatile("s_waitcnt vmcnt(4)" ::: "memory");
                else             asm volatile("s_waitcnt vmcnt(0)" ::: "memory");
            }
            __builtin_amdgcn_s_barrier();     // B1: tile data visible / regions freed
            if (q == 0) {
#pragma unroll
                for (int ks = 0; ks < 2; ks++)
#pragma unroll
                    for (int j = 0; j < 4; j++) {
                        int r = wn + j * 16 + lo;
                        bw[ks][j] = *(const bf16x8*)&Bb[r * 64 +
                                        ((ks * 4 + quad) ^ (r & 7)) * 8];
                    }
            }
            bf16x8 af[2][2];
#pragma unroll
            for (int ks = 0; ks < 2; ks++)
#pragma unroll
                for (int ii = 0; ii < 2; ii++) {
                    int r = wm + (q * 2 + ii) * 16 + lo;
                    af[ks][ii] = *(const bf16x8*)&At[r * 64 +
                                      ((ks * 4 + quad) ^ (r & 7)) * 8];
                }
            if      (q == 0 && kt + 1 < NT) stageHalf(0, kt + 1, 0);
            else if (q == 1 && kt + 1 < NT) stageHalf(0, kt + 1, 1);
            else if (q == 2 && kt + 2 < NT) stageHalf(1, kt + 2, 0);
            else if (q == 3 && kt + 2 < NT) stageHalf(1, kt + 2, 1);
            asm volatile("s_waitcnt lgkmcnt(0)" ::: "memory");
            __builtin_amdgcn_s_barrier();     // B2: phase reads served
            __builtin_amdgcn_sched_barrier(0);
            __builtin_amdgcn_s_setprio(1);
#pragma unroll
            for (int ks = 0; ks < 2; ks++)
#pragma unroll
                for (int ii = 0; ii < 2; ii++)
#pragma unroll
                    for (int j = 0; j < 4; j++)
                        acc[q * 2 + ii][j] = __builtin_amdgcn_mfma_f32_16x16x32_bf16(
                            af[ks][ii], bw[ks][j], acc[q * 2 + ii][j], 0, 0, 0);
            __builtin_amdgcn_s_setprio(0);
        }
    }
}

// GEMM1: qkv = Xb @ Wqkv_t^T + b.  Q scattered to [bh][t][d] PRE-SCALED by
// (1/sqrt(dk))*log2(e); K to [bh][t][d]; V TRANSPOSED to [bh][d][t].
// 256x256 tile, 8-phase core. Grid (12, 32) = 384 blocks.
__global__ __launch_bounds__(512, 2) void gemm1_mfma(const u16* __restrict__ A,
                                                     const u16* __restrict__ Bt,
                                                     const float* __restrict__ bias,
                                                     u16* __restrict__ qkv) {
    __shared__ u16 pool[2 * 32768];          // 128 KB
    const int tid = threadIdx.x;
    const int lane = tid & 63, wv = tid >> 6;
    const int lo = lane & 15, quad = lane >> 4;
    // XCD swizzle: 384 = 8 XCD x 3 patches x (4m x 4n)
    int lin = blockIdx.y * 12 + blockIdx.x;
    int xcd = lin & 7, ord = lin >> 3;       // ord 0..47
    int patch = ord >> 4, loc = ord & 15;
    const int m0 = (xcd * 4 + (loc >> 2)) * 256;
    const int n0 = (patch * 4 + (loc & 3)) * 256;
    const int wm = (wv >> 2) * 128, wn = (wv & 3) * 64;  // 2M x 4N waves
    const float scale2 = 0.18033688011112042f;  // (1/8) * log2(e)
    f32x4 acc[8][4] = {};

    gemm_core_8ph<1024>(A, Bt, pool, m0, n0, wm, wn, tid, lo, quad, acc);

    const int whichw = (n0 + wn) >> 10;   // uniform per wave (0=Q,1=K,2=V)
    if (whichw == 2) {
        // V plane: [bh][d][t], pack 4 consecutive t per store
#pragma unroll
        for (int i = 0; i < 8; i++) {
            int mb = m0 + wm + i * 16 + quad * 4;
            int b = mb >> 11, t = mb & 2047;
#pragma unroll
            for (int j = 0; j < 4; j++) {
                int n = n0 + wn + j * 16 + lo;
                int rem = n & 1023;
                int h = rem >> 6, d = rem & 63;
                float bn = bias[n];
                ushort4 o;
                o.x = f2bf(acc[i][j][0] + bn);
                o.y = f2bf(acc[i][j][1] + bn);
                o.z = f2bf(acc[i][j][2] + bn);
                o.w = f2bf(acc[i][j][3] + bn);
                *(ushort4*)&qkv[2 * PHT +
                                (((size_t)(b * HEADS + h) * DK + d) * TSEQ + t)] = o;
            }
        }
    } else {
        const float sc = (whichw == 0) ? scale2 : 1.0f;
#pragma unroll
        for (int i = 0; i < 8; i++) {
#pragma unroll
            for (int r = 0; r < 4; r++) {
                int m = m0 + wm + i * 16 + quad * 4 + r;
                int b = m >> 11, t = m & 2047;
#pragma unroll
                for (int j = 0; j < 4; j++) {
                    int n = n0 + wn + j * 16 + lo;
                    float v = (acc[i][j][r] + bias[n]) * sc;
                    int rem = n & 1023;
                    int h = rem >> 6, d = rem & 63;
                    qkv[(size_t)whichw * PHT +
                        (((size_t)(b * HEADS + h) * TSEQ + t) * DK + d)] = f2bf(v);
                }
            }
        }
    }
}

// GEMM2: out = AO @ Wo_t^T + b (fp32 out). v3 core, 256 blocks (full round).
__global__ __launch_bounds__(512, 1) void gemm2_mfma(const u16* __restrict__ A,
                                                     const u16* __restrict__ Bt,
                                                     const float* __restrict__ bias,
                                                     float* __restrict__ out) {
    __shared__ u16 pool[3 * 24576];
    const int tid = threadIdx.x;
    const int lane = tid & 63, wv = tid >> 6;
    const int lo = lane & 15, quad = lane >> 4;
    // L2-patch XCD swizzle: 32 blocks/XCD = one 8m x 4n patch
    int lin = blockIdx.y * 4 + blockIdx.x;
    int xcd = lin & 7, ord = lin >> 3;       // ord 0..31
    const int m0 = (xcd * 8 + (ord >> 2)) * 128;
    const int n0 = (ord & 3) * 256;
    const int wm = (wv >> 2) * 64, wn = (wv & 3) * 64;
    f32x4 acc[4][4] = {};

    gemm_core256<1024>(A, Bt, pool, m0, n0, wm, wn, tid, lo, quad, acc);

#pragma unroll
    for (int i = 0; i < 4; i++) {
#pragma unroll
        for (int r = 0; r < 4; r++) {
            int m = m0 + wm + i * 16 + quad * 4 + r;
#pragma unroll
            for (int j = 0; j < 4; j++) {
                int n = n0 + wn + j * 16 + lo;
                out[(size_t)m * EMB + n] = acc[i][j][r] + bias[n];
            }
        }
    }
}

// ---------------------------------------------------------------------------
// MFMA flash attention v8 (verified 61.5us, VGPR 64, 4 waves/SIMD).
// One q-tile (128 rows) per block: grid (bh=64, qt=16) = 1024 blocks = 4/CU;
// KVBLK=64 -> LDS 32KB; launch_bounds(256,4) -> 4 waves/SIMD TLP.
// In-register P (32x32x16 swapped QK^T + cvt_pk + permlane32_swap).
// Q (pre-scaled), K: [bh][t][d].  V: [bh][d][t].  Out: [B][T][H][64] bf16.
// ---------------------------------------------------------------------------
__global__ __launch_bounds__(256, 4) void attn_mfma(const u16* __restrict__ Qg,
                                                    const u16* __restrict__ Kg,
                                                    const u16* __restrict__ Vg,
                                                    u16* __restrict__ AO) {
    __shared__ u16 pool[4 * 4096];   // K[2] 16KB | V[2] 16KB  (KVBLK=64)

    const int tid = threadIdx.x;
    const int lane = tid & 63, wv = tid >> 6;
    const int c = lane & 31, hf = lane >> 5;
    const int bh = blockIdx.x;
    const int qt = 15 - blockIdx.y;          // descending: long blocks first
    const size_t base = (size_t)bh * TSEQ * DK;
    const int b = bh >> 4, h = bh & 15;
    const int q0 = qt * 128;
    const int ktmax = 2 * qt + 1;            // 64-key tiles: 0..ktmax
    const bf16x8 onesf = {0x3F80, 0x3F80, 0x3F80, 0x3F80,
                          0x3F80, 0x3F80, 0x3F80, 0x3F80};

    auto stageKV = [&](int kt2, int bufsel) {
        u16* Kd = pool + bufsel * 4096;
        u16* Vd = pool + 2 * 4096 + bufsel * 4096;
#pragma unroll
        for (int cc = 0; cc < 2; cc++) {
            int chunk = cc * 256 + tid;
            int row = chunk >> 3, p = chunk & 7;
            int pg = p ^ (row & 7);
            gl2lds16(Kg + base + (size_t)(kt2 * 64 + row) * DK + pg * 8,
                     Kd + chunk * 8);
        }
#pragma unroll
        for (int cc = 0; cc < 2; cc++) {
            int chunk = cc * 256 + tid;
            int row = chunk >> 3, p = chunk & 7;   // row = d index
            int pg = p ^ (row & 7);
            gl2lds16(Vg + base + (size_t)row * TSEQ + kt2 * 64 + pg * 8,
                     Vd + chunk * 8);
        }
    };

    stageKV(0, 0);
    bf16x8 bq[4];
#pragma unroll
    for (int s = 0; s < 4; s++)
        bq[s] = *(const bf16x8*)&Qg[base + (size_t)(q0 + wv * 32 + c) * DK +
                                    s * 16 + hf * 8];
    __syncthreads();  // K0/V0 in LDS (drains vmcnt); bq in regs

    f32x16 O0 = {}, O1 = {}, ls = {};
    const int wrow = q0 + wv * 32;           // wave's first q-row

    for (int kt = 0; kt <= ktmax; kt++) {
        const int cur = kt & 1;
        if (kt) __syncthreads();
        if (kt < ktmax) stageKV(kt + 1, cur ^ 1);
        const u16* Ksc = pool + cur * 4096;
        const u16* Vtc = pool + 2 * 4096 + cur * 4096;

#pragma unroll
        for (int j = 0; j < 2; j++) {
            const int kb = kt * 64 + j * 32;
            if (kb <= wrow + 31) {
                f32x16 st = {};
#pragma unroll
                for (int s = 0; s < 4; s++) {
                    int row = j * 32 + c;
                    bf16x8 ak = *(const bf16x8*)&Ksc[row * 64 +
                                    (((s << 1) + hf) ^ (row & 7)) * 8];
                    st = __builtin_amdgcn_mfma_f32_32x32x16_bf16(
                        ak, bq[s], st, 0, 0, 0);
                }
                const bool part = (kb + 31 > wrow);
                const int thr = wrow + c - kb;
#pragma unroll
                for (int r = 0; r < 16; r++) {
                    float e = __builtin_amdgcn_exp2f(st[r]);
                    if (part) {
                        int ko = (r & 3) + 8 * (r >> 2) + 4 * hf;
                        if (ko > thr) e = 0.f;
                    }
                    st[r] = e;
                }
#pragma unroll
                for (int ks = 0; ks < 2; ks++) {
                    const int br = ks * 8;
                    unsigned int w0 = pk2bf(st[br + 0], st[br + 1]);
                    unsigned int w1 = pk2bf(st[br + 2], st[br + 3]);
                    unsigned int w2 = pk2bf(st[br + 4], st[br + 5]);
                    unsigned int w3 = pk2bf(st[br + 6], st[br + 7]);
                    asm volatile("v_permlane32_swap_b32 %0, %1"
                                 : "+v"(w0), "+v"(w2));
                    asm volatile("v_permlane32_swap_b32 %0, %1"
                                 : "+v"(w1), "+v"(w3));
                    union { u32x4 w; bf16x8 v; } pu;
                    pu.w[0] = w0; pu.w[1] = w1; pu.w[2] = w2; pu.w[3] = w3;
                    const int p0 = j * 4 + ks * 2 + hf;
                    bf16x8 bv0 = *(const bf16x8*)&Vtc[c * 64 +
                                    (p0 ^ (c & 7)) * 8];
                    bf16x8 bv1 = *(const bf16x8*)&Vtc[(32 + c) * 64 +
                                    (p0 ^ (c & 7)) * 8];
                    O0 = __builtin_amdgcn_mfma_f32_32x32x16_bf16(
                        pu.v, bv0, O0, 0, 0, 0);
                    O1 = __builtin_amdgcn_mfma_f32_32x32x16_bf16(
                        pu.v, bv1, O1, 0, 0, 0);
                    ls = __builtin_amdgcn_mfma_f32_32x32x16_bf16(
                        pu.v, onesf, ls, 0, 0, 0);
                }
            }
        }
    }

#pragma unroll
    for (int r = 0; r < 16; r++) {
        int qrow = q0 + wv * 32 + (r & 3) + 8 * (r >> 2) + 4 * hf;
        float inv = 1.f / ls[r];
        size_t o = (((size_t)b * TSEQ + qrow) * HEADS + h) * DK;
        AO[o + c]      = f2bf(O0[r] * inv);
        AO[o + 32 + c] = f2bf(O1[r] * inv);
    }
}

// ---------------------------------------------------------------------------
extern "C" void kernel_launch(void* const* d_in, const int* in_sizes, int n_in,
                              void* d_out, int out_size, void* d_ws, size_t ws_size,
                              hipStream_t stream) {
    const float* x    = (const float*)d_in[0];
    const float* Wqkv = (const float*)d_in[1];
    const float* bqkv = (const float*)d_in[2];
    const float* Wo   = (const float*)d_in[3];
    const float* bo   = (const float*)d_in[4];
    float* out = (float*)d_out;

    // workspace layout (u16 elems): [Xb 8.4M | Wt 3.1M | Wot 1M | QKV 25.2M]
    u16* Xb  = (u16*)d_ws;
    u16* Wt  = Xb + PHT;                    // [3072][1024]
    u16* Wot = Wt + (size_t)NQKV * EMB;     // [1024][1024]
    u16* qkv = Wot + (size_t)EMB * EMB;     // Q,K: [bh][t][d]; V: [bh][d][t]
    u16* AO  = Xb;                          // overlay: Xb dead after gemm1

    convert_x<<<MROWS * EMB / 1024, 256, 0, stream>>>(x, Xb);
    transpose_both<<<dim3(96 + 32, 32), 256, 0, stream>>>(Wqkv, Wo, Wt, Wot);

    gemm1_mfma<<<dim3(NQKV / 256, MROWS / 256), 512, 0, stream>>>(Xb, Wt, bqkv, qkv);
    attn_mfma<<<dim3(BATCH * HEADS, 16), 256, 0, stream>>>(
        qkv, qkv + PHT, qkv + 2 * PHT, AO);
    gemm2_mfma<<<dim3(EMB / 256, MROWS / 128), 512, 0, stream>>>(AO, Wot, bo, out);
}

// Round 19
// 230.392 us; speedup vs baseline: 1.0499x; 1.0499x over previous
//
#include <hip/hip_runtime.h>
#include <hip/hip_bf16.h>
#include <math.h>

typedef unsigned short u16;
typedef __attribute__((ext_vector_type(8))) short bf16x8;
typedef __attribute__((ext_vector_type(4))) float f32x4;
typedef __attribute__((ext_vector_type(16))) float f32x16;
typedef __attribute__((ext_vector_type(4))) unsigned int u32x4;

#define BATCH 4
#define TSEQ  2048
#define HEADS 16
#define DK    64
#define EMB   1024
#define MROWS 8192            // B*T
#define NQKV  3072
#define PHT   ((size_t)MROWS * EMB)   // 8388608 elems per Q/K/V plane

__device__ __forceinline__ u16 f2bf(float f) {
    union { float f; unsigned int i; } v;
    v.f = f;
    unsigned int x = v.i;
    return (u16)((x + 0x7FFFu + ((x >> 16) & 1u)) >> 16);  // RNE
}

// packed 2xfp32 -> 2xbf16 (RNE) in one u32
__device__ __forceinline__ unsigned int pk2bf(float a, float b) {
    float2 f2; f2.x = a; f2.y = b;
    union { __hip_bfloat162 h; unsigned int u; } cv;
    cv.h = __float22bfloat162_rn(f2);
    return cv.u;
}

// async 16B global->LDS (dest = wave-uniform base + lane*16)
__device__ __forceinline__ void gl2lds16(const u16* g, u16* l) {
    __builtin_amdgcn_global_load_lds(
        (const __attribute__((address_space(1))) unsigned int*)g,
        (__attribute__((address_space(3))) unsigned int*)l, 16, 0, 0);
}

// ---------------------------------------------------------------------------
// prep: fp32 -> bf16 convert (X); both weight transposes in ONE launch
// ---------------------------------------------------------------------------
__global__ __launch_bounds__(256) void convert_x(const float* __restrict__ X,
                                                 u16* __restrict__ Xb) {
    int i = (blockIdx.x * 256 + threadIdx.x) * 4;
    float4 v = *(const float4*)&X[i];
    ushort4 o;
    o.x = f2bf(v.x); o.y = f2bf(v.y); o.z = f2bf(v.z); o.w = f2bf(v.w);
    *(ushort4*)&Xb[i] = o;
}

// bx < 96 -> Wqkv (N=3072); else Wo (N=1024). K=1024 for both.
__global__ __launch_bounds__(256) void transpose_both(const float* __restrict__ Wqkv,
                                                      const float* __restrict__ Wo,
                                                      u16* __restrict__ Wt,
                                                      u16* __restrict__ Wot) {
    __shared__ float tile[32][33];
    const int tx = threadIdx.x & 31, ty = threadIdx.x >> 5;  // 32 x 8
    const int K = 1024;
    const float* W;
    u16* D;
    int N, bx;
    if (blockIdx.x < 96) { W = Wqkv; D = Wt; N = 3072; bx = blockIdx.x; }
    else                 { W = Wo;   D = Wot; N = 1024; bx = blockIdx.x - 96; }
    const int by = blockIdx.y;
#pragma unroll
    for (int s = 0; s < 4; s++)
        tile[ty + 8 * s][tx] = W[(size_t)(by * 32 + ty + 8 * s) * N + bx * 32 + tx];
    __syncthreads();
#pragma unroll
    for (int s = 0; s < 4; s++)
        D[(size_t)(bx * 32 + ty + 8 * s) * K + by * 32 + tx] = f2bf(tile[tx][ty + 8 * s]);
}

// ---------------------------------------------------------------------------
// MFMA GEMM core v3 (verified best: ~62us gemm1 / ~837 TF; v4 and the
// 8-phase port both regressed — R16: 65.3us, R18: 89.5us).
// 128x256 tile, BK=64, 8 waves, triple-buffered LDS + counted vmcnt +
// register-fragment double-buffer (ONE barrier per K-tile).
// ---------------------------------------------------------------------------
template <int KDIM>
__device__ __forceinline__ void gemm_core256(const u16* __restrict__ A,
                                             const u16* __restrict__ Bt,
                                             u16* pool,
                                             int m0, int n0, int wm, int wn,
                                             int tid, int lo, int quad,
                                             f32x4 (&acc)[4][4]) {
    constexpr int NT = KDIM / 64;          // 16 K-tiles
    static_assert(NT >= 4 && (NT % 2) == 0, "NT even, >=4");

    // per-thread running global pointers (advance 64 elems per staged tile)
    const u16* ga[2];
    const u16* gb[4];
#pragma unroll
    for (int c = 0; c < 2; c++) {
        int chunk = c * 512 + tid, row = chunk >> 3, p = chunk & 7;
        ga[c] = A + (size_t)(m0 + row) * KDIM + (p ^ (row & 7)) * 8;
    }
#pragma unroll
    for (int c = 0; c < 4; c++) {
        int chunk = c * 512 + tid, row = chunk >> 3, p = chunk & 7;
        gb[c] = Bt + (size_t)(n0 + row) * KDIM + (p ^ (row & 7)) * 8;
    }

    auto stage = [&](int b) {   // 6 gl2lds per thread -> vmcnt +6
        u16* As = pool + b * 24576;
        u16* Bs = As + 8192;
#pragma unroll
        for (int c = 0; c < 2; c++) {
            gl2lds16(ga[c], As + (size_t)(c * 512 + tid) * 8);
            ga[c] += 64;
        }
#pragma unroll
        for (int c = 0; c < 4; c++) {
            gl2lds16(gb[c], Bs + (size_t)(c * 512 + tid) * 8);
            gb[c] += 64;
        }
    };

    bf16x8 afA[2][4], bwA[2][4], afB[2][4], bwB[2][4];

    auto ldfrag = [&](int b, bf16x8 (&af)[2][4], bf16x8 (&bw)[2][4]) {
        const u16* As = pool + b * 24576;
        const u16* Bs = As + 8192;
#pragma unroll
        for (int ks = 0; ks < 2; ks++) {
#pragma unroll
            for (int i = 0; i < 4; i++) {
                int r = wm + i * 16 + lo;
                af[ks][i] = *(const bf16x8*)&As[r * 64 + ((ks * 4 + quad) ^ (r & 7)) * 8];
            }
#pragma unroll
            for (int j = 0; j < 4; j++) {
                int r = wn + j * 16 + lo;
                bw[ks][j] = *(const bf16x8*)&Bs[r * 64 + ((ks * 4 + quad) ^ (r & 7)) * 8];
            }
        }
    };

    auto domfma = [&](bf16x8 (&af)[2][4], bf16x8 (&bw)[2][4]) {
        __builtin_amdgcn_sched_barrier(0);   // keep prefetch ds_reads above MFMA
        __builtin_amdgcn_s_setprio(1);
#pragma unroll
        for (int ks = 0; ks < 2; ks++)
#pragma unroll
            for (int i = 0; i < 4; i++)
#pragma unroll
                for (int j = 0; j < 4; j++)
                    acc[i][j] = __builtin_amdgcn_mfma_f32_16x16x32_bf16(
                        af[ks][i], bw[ks][j], acc[i][j], 0, 0, 0);
        __builtin_amdgcn_s_setprio(0);
    };

    // prologue: fill 3 buffers; read tile-0 fragments into set A
    stage(0); stage(1); stage(2);            // 18 loads in flight
    asm volatile("s_waitcnt vmcnt(12)" ::: "memory");  // my tile-0 loads landed
    __builtin_amdgcn_s_barrier();            // everyone's tile 0 in LDS
    ldfrag(0, afA, bwA);

#pragma unroll
    for (int kt = 0; kt < NT; kt++) {
        if (kt < NT - 1) {
            asm volatile("s_waitcnt lgkmcnt(0)" ::: "memory");   // frags(kt) done
            if (kt < NT - 2)
                asm volatile("s_waitcnt vmcnt(6)" ::: "memory"); // tile kt+1 landed
            else
                asm volatile("s_waitcnt vmcnt(0)" ::: "memory"); // last tile landed
            __builtin_amdgcn_s_barrier();    // collective free + visible
            if (kt + 3 < NT) stage(kt % 3);  // tile kt+3 into freed buffer
            if (kt & 1) ldfrag((kt + 1) % 3, afA, bwA);
            else        ldfrag((kt + 1) % 3, afB, bwB);
        }
        if (kt & 1) domfma(afB, bwB);
        else        domfma(afA, bwA);
    }
}

// GEMM1: qkv = Xb @ Wqkv_t^T + b.  Q scattered to [bh][t][d] PRE-SCALED by
// (1/sqrt(dk))*log2(e); K to [bh][t][d]; V TRANSPOSED to [bh][d][t].
__global__ __launch_bounds__(512, 1) void gemm1_mfma(const u16* __restrict__ A,
                                                     const u16* __restrict__ Bt,
                                                     const float* __restrict__ bias,
                                                     u16* __restrict__ qkv) {
    __shared__ u16 pool[3 * 24576];          // 144 KB
    const int tid = threadIdx.x;
    const int lane = tid & 63, wv = tid >> 6;
    const int lo = lane & 15, quad = lane >> 4;
    // L2-patch XCD swizzle: 768 blocks = 8 XCD x 3 patches x (8m x 4n).
    // (R6/R8 verified: FETCH 84->49MB)
    int lin = blockIdx.y * 12 + blockIdx.x;
    int xcd = lin & 7, ord = lin >> 3;       // ord 0..95 sequential on this XCD
    int patch = ord >> 5, loc = ord & 31;    // 3 patches of 32 blocks
    const int m0 = (xcd * 8 + (loc >> 2)) * 128;   // 8 m-rows per XCD (A hot)
    const int n0 = (patch * 4 + (loc & 3)) * 256;  // 4 n-cols per patch
    const int wm = (wv >> 2) * 64, wn = (wv & 3) * 64;   // 2M x 4N waves
    const float scale2 = 0.18033688011112042f;  // (1/8) * log2(e)
    f32x4 acc[4][4] = {};

    gemm_core256<1024>(A, Bt, pool, m0, n0, wm, wn, tid, lo, quad, acc);

    const int whichw = (n0 + wn) >> 10;   // uniform per wave (0=Q,1=K,2=V)
    if (whichw == 2) {
        // V plane: [bh][d][t], pack 4 consecutive t (C-layout rows) per store
#pragma unroll
        for (int i = 0; i < 4; i++) {
            int mb = m0 + wm + i * 16 + quad * 4;
            int b = mb >> 11, t = mb & 2047;
#pragma unroll
            for (int j = 0; j < 4; j++) {
                int n = n0 + wn + j * 16 + lo;
                int rem = n & 1023;
                int h = rem >> 6, d = rem & 63;
                float bn = bias[n];
                ushort4 o;
                o.x = f2bf(acc[i][j][0] + bn);
                o.y = f2bf(acc[i][j][1] + bn);
                o.z = f2bf(acc[i][j][2] + bn);
                o.w = f2bf(acc[i][j][3] + bn);
                *(ushort4*)&qkv[2 * PHT +
                                (((size_t)(b * HEADS + h) * DK + d) * TSEQ + t)] = o;
            }
        }
    } else {
        const float sc = (whichw == 0) ? scale2 : 1.0f;
#pragma unroll
        for (int i = 0; i < 4; i++) {
#pragma unroll
            for (int r = 0; r < 4; r++) {
                int m = m0 + wm + i * 16 + quad * 4 + r;
                int b = m >> 11, t = m & 2047;
#pragma unroll
                for (int j = 0; j < 4; j++) {
                    int n = n0 + wn + j * 16 + lo;
                    float v = (acc[i][j][r] + bias[n]) * sc;
                    int rem = n & 1023;
                    int h = rem >> 6, d = rem & 63;
                    qkv[(size_t)whichw * PHT +
                        (((size_t)(b * HEADS + h) * TSEQ + t) * DK + d)] = f2bf(v);
                }
            }
        }
    }
}

// GEMM2: out = AO @ Wo_t^T + b (fp32 out). 256 blocks = 8 XCD x (8m x 4n).
__global__ __launch_bounds__(512, 1) void gemm2_mfma(const u16* __restrict__ A,
                                                     const u16* __restrict__ Bt,
                                                     const float* __restrict__ bias,
                                                     float* __restrict__ out) {
    __shared__ u16 pool[3 * 24576];
    const int tid = threadIdx.x;
    const int lane = tid & 63, wv = tid >> 6;
    const int lo = lane & 15, quad = lane >> 4;
    // L2-patch XCD swizzle: 32 blocks/XCD = one 8m x 4n patch (A 2MB + B 2MB)
    int lin = blockIdx.y * 4 + blockIdx.x;
    int xcd = lin & 7, ord = lin >> 3;       // ord 0..31
    const int m0 = (xcd * 8 + (ord >> 2)) * 128;
    const int n0 = (ord & 3) * 256;
    const int wm = (wv >> 2) * 64, wn = (wv & 3) * 64;
    f32x4 acc[4][4] = {};

    gemm_core256<1024>(A, Bt, pool, m0, n0, wm, wn, tid, lo, quad, acc);

#pragma unroll
    for (int i = 0; i < 4; i++) {
#pragma unroll
        for (int r = 0; r < 4; r++) {
            int m = m0 + wm + i * 16 + quad * 4 + r;
#pragma unroll
            for (int j = 0; j < 4; j++) {
                int n = n0 + wn + j * 16 + lo;
                out[(size_t)m * EMB + n] = acc[i][j][r] + bias[n];
            }
        }
    }
}

// ---------------------------------------------------------------------------
// MFMA flash attention v8 (verified 61.5us, VGPR 64, 4 waves/SIMD).
// One q-tile (128 rows) per block: grid (bh=64, qt=16) = 1024 blocks = 4/CU;
// KVBLK=64 -> LDS 32KB; launch_bounds(256,4) -> 4 waves/SIMD TLP.
// qt = 15 - blockIdx.y: longest blocks dispatch first.
// XCD locality: lin%8 = bh%8 (16 qt-blocks of one bh share an XCD L2).
// In-register P (32x32x16 swapped QK^T + cvt_pk + permlane32_swap).
// Q (pre-scaled), K: [bh][t][d].  V: [bh][d][t].  Out: [B][T][H][64] bf16.
// ---------------------------------------------------------------------------
__global__ __launch_bounds__(256, 4) void attn_mfma(const u16* __restrict__ Qg,
                                                    const u16* __restrict__ Kg,
                                                    const u16* __restrict__ Vg,
                                                    u16* __restrict__ AO) {
    __shared__ u16 pool[4 * 4096];   // K[2] 16KB | V[2] 16KB  (KVBLK=64)

    const int tid = threadIdx.x;
    const int lane = tid & 63, wv = tid >> 6;
    const int c = lane & 31, hf = lane >> 5;
    const int bh = blockIdx.x;
    const int qt = 15 - blockIdx.y;          // descending: long blocks first
    const size_t base = (size_t)bh * TSEQ * DK;
    const int b = bh >> 4, h = bh & 15;
    const int q0 = qt * 128;
    const int ktmax = 2 * qt + 1;            // 64-key tiles: 0..ktmax
    const bf16x8 onesf = {0x3F80, 0x3F80, 0x3F80, 0x3F80,
                          0x3F80, 0x3F80, 0x3F80, 0x3F80};

    // stage K(kt2) and V^T(kt2) (64 keys each) into buffer bufsel.
    auto stageKV = [&](int kt2, int bufsel) {
        u16* Kd = pool + bufsel * 4096;
        u16* Vd = pool + 2 * 4096 + bufsel * 4096;
#pragma unroll
        for (int cc = 0; cc < 2; cc++) {
            int chunk = cc * 256 + tid;
            int row = chunk >> 3, p = chunk & 7;
            int pg = p ^ (row & 7);
            gl2lds16(Kg + base + (size_t)(kt2 * 64 + row) * DK + pg * 8,
                     Kd + chunk * 8);
        }
#pragma unroll
        for (int cc = 0; cc < 2; cc++) {
            int chunk = cc * 256 + tid;
            int row = chunk >> 3, p = chunk & 7;   // row = d index
            int pg = p ^ (row & 7);
            gl2lds16(Vg + base + (size_t)row * TSEQ + kt2 * 64 + pg * 8,
                     Vd + chunk * 8);
        }
    };

    stageKV(0, 0);
    // Q B-fragments direct from global (kt-invariant):
    // lane (c,hf) holds Q[qrow = q0+wv*32+c][dk = s*16 + hf*8 + e]
    bf16x8 bq[4];
#pragma unroll
    for (int s = 0; s < 4; s++)
        bq[s] = *(const bf16x8*)&Qg[base + (size_t)(q0 + wv * 32 + c) * DK +
                                    s * 16 + hf * 8];
    __syncthreads();  // K0/V0 in LDS (drains vmcnt); bq in regs

    f32x16 O0 = {}, O1 = {}, ls = {};
    const int wrow = q0 + wv * 32;           // wave's first q-row

    for (int kt = 0; kt <= ktmax; kt++) {
        const int cur = kt & 1;
        if (kt) __syncthreads();             // all waves done kt-1; prefetch(kt) landed
        if (kt < ktmax) stageKV(kt + 1, cur ^ 1);  // flies across kt's compute
        const u16* Ksc = pool + cur * 4096;
        const u16* Vtc = pool + 2 * 4096 + cur * 4096;

#pragma unroll
        for (int j = 0; j < 2; j++) {
            const int kb = kt * 64 + j * 32;     // key base of this 32-key tile
            if (kb <= wrow + 31) {               // skip fully-masked tiles
                // QK^T for 32-key tile j: st = S^T[key][qrow=c]
                f32x16 st = {};
#pragma unroll
                for (int s = 0; s < 4; s++) {
                    int row = j * 32 + c;
                    bf16x8 ak = *(const bf16x8*)&Ksc[row * 64 +
                                    (((s << 1) + hf) ^ (row & 7)) * 8];
                    st = __builtin_amdgcn_mfma_f32_32x32x16_bf16(
                        ak, bq[s], st, 0, 0, 0);
                }
                // P = exp2(S) (no max); mask only partially-covered tiles
                const bool part = (kb + 31 > wrow);
                const int thr = wrow + c - kb;   // mask keys ko > thr
#pragma unroll
                for (int r = 0; r < 16; r++) {
                    float e = __builtin_amdgcn_exp2f(st[r]);
                    if (part) {
                        int ko = (r & 3) + 8 * (r >> 2) + 4 * hf;  // key in tile
                        if (ko > thr) e = 0.f;
                    }
                    st[r] = e;
                }
                // PV: 2 k-steps of 16 keys; PA built in-register
#pragma unroll
                for (int ks = 0; ks < 2; ks++) {
                    const int br = ks * 8;
                    unsigned int w0 = pk2bf(st[br + 0], st[br + 1]);
                    unsigned int w1 = pk2bf(st[br + 2], st[br + 3]);
                    unsigned int w2 = pk2bf(st[br + 4], st[br + 5]);
                    unsigned int w3 = pk2bf(st[br + 6], st[br + 7]);
                    // swap(D=w0,S=w2): w0'<-word0 (both halves), w2'<-word2
                    asm volatile("v_permlane32_swap_b32 %0, %1"
                                 : "+v"(w0), "+v"(w2));
                    asm volatile("v_permlane32_swap_b32 %0, %1"
                                 : "+v"(w1), "+v"(w3));
                    union { u32x4 w; bf16x8 v; } pu;
                    pu.w[0] = w0; pu.w[1] = w1; pu.w[2] = w2; pu.w[3] = w3;
                    // V B-fragments: lane (c,hf) reads V^T[d][8 keys]
                    const int p0 = j * 4 + ks * 2 + hf;   // key chunk 0..7
                    bf16x8 bv0 = *(const bf16x8*)&Vtc[c * 64 +
                                    (p0 ^ (c & 7)) * 8];
                    bf16x8 bv1 = *(const bf16x8*)&Vtc[(32 + c) * 64 +
                                    (p0 ^ (c & 7)) * 8];
                    O0 = __builtin_amdgcn_mfma_f32_32x32x16_bf16(
                        pu.v, bv0, O0, 0, 0, 0);
                    O1 = __builtin_amdgcn_mfma_f32_32x32x16_bf16(
                        pu.v, bv1, O1, 0, 0, 0);
                    ls = __builtin_amdgcn_mfma_f32_32x32x16_bf16(
                        pu.v, onesf, ls, 0, 0, 0);
                }
            }
        }
    }

    // epilogue: normalize by l, store [B][T][H][DK] bf16
#pragma unroll
    for (int r = 0; r < 16; r++) {
        int qrow = q0 + wv * 32 + (r & 3) + 8 * (r >> 2) + 4 * hf;
        float inv = 1.f / ls[r];
        size_t o = (((size_t)b * TSEQ + qrow) * HEADS + h) * DK;
        AO[o + c]      = f2bf(O0[r] * inv);
        AO[o + 32 + c] = f2bf(O1[r] * inv);
    }
}

// ---------------------------------------------------------------------------
extern "C" void kernel_launch(void* const* d_in, const int* in_sizes, int n_in,
                              void* d_out, int out_size, void* d_ws, size_t ws_size,
                              hipStream_t stream) {
    const float* x    = (const float*)d_in[0];
    const float* Wqkv = (const float*)d_in[1];
    const float* bqkv = (const float*)d_in[2];
    const float* Wo   = (const float*)d_in[3];
    const float* bo   = (const float*)d_in[4];
    float* out = (float*)d_out;

    // workspace layout (u16 elems): [Xb 8.4M | Wt 3.1M | Wot 1M | QKV 25.2M]
    u16* Xb  = (u16*)d_ws;
    u16* Wt  = Xb + PHT;                    // [3072][1024]
    u16* Wot = Wt + (size_t)NQKV * EMB;     // [1024][1024]
    u16* qkv = Wot + (size_t)EMB * EMB;     // Q,K: [bh][t][d]; V: [bh][d][t]
    u16* AO  = Xb;                          // overlay: Xb dead after gemm1

    convert_x<<<MROWS * EMB / 1024, 256, 0, stream>>>(x, Xb);
    transpose_both<<<dim3(96 + 32, 32), 256, 0, stream>>>(Wqkv, Wo, Wt, Wot);

    gemm1_mfma<<<dim3(NQKV / 256, MROWS / 128), 512, 0, stream>>>(Xb, Wt, bqkv, qkv);
    attn_mfma<<<dim3(BATCH * HEADS, 16), 256, 0, stream>>>(
        qkv, qkv + PHT, qkv + 2 * PHT, AO);
    gemm2_mfma<<<dim3(EMB / 256, MROWS / 128), 512, 0, stream>>>(AO, Wot, bo, out);
}